// Round 10
// baseline (8465.540 us; speedup 1.0000x reference)
//
#include <hip/hip_runtime.h>
#include <hip/hip_bf16.h>

#define BT 2048
#define VOC 32000
#define IGN (-100)

typedef __attribute__((ext_vector_type(4))) float f32x4;
typedef __attribute__((ext_vector_type(8))) short s16x8;
typedef __attribute__((ext_vector_type(4))) unsigned int u32x4;

#define AS1 __attribute__((address_space(1)))
#define AS3 __attribute__((address_space(3)))

__device__ __forceinline__ unsigned short f2bf(float f) {
    union { __hip_bfloat16 h; unsigned short u; } c;
    c.h = __float2bfloat16(f);
    return c.u;
}
__device__ __forceinline__ float bf2f(unsigned short u) {
    union { unsigned int u; float f; } c;
    c.u = ((unsigned int)u) << 16;
    return c.f;
}
__device__ __forceinline__ unsigned int pk2(float a, float b) {
    return (unsigned int)f2bf(a) | ((unsigned int)f2bf(b) << 16);
}

// ---------------------------------------------------------------------------
// fp32 -> bf16 pre-convert, row-major
// ---------------------------------------------------------------------------
__global__ __launch_bounds__(256)
void cvt_kernel(const float* __restrict__ in, unsigned short* __restrict__ out, int n8) {
    for (int i = blockIdx.x * 256 + threadIdx.x; i < n8; i += gridDim.x * 256) {
        f32x4 a = ((const f32x4*)in)[2 * i];
        f32x4 b = ((const f32x4*)in)[2 * i + 1];
        u32x4 o;
        o[0] = pk2(a[0], a[1]);
        o[1] = pk2(a[2], a[3]);
        o[2] = pk2(b[0], b[1]);
        o[3] = pk2(b[2], b[3]);
        ((u32x4*)out)[i] = o;
    }
}

// ---------------------------------------------------------------------------
// 256x256 GEMM (bf16 operands), 2-region K-half double-buffer, 64 KiB LDS ->
// TWO independent blocks per CU (the round-6 ring at 128 KiB locked us to one
// barrier-locked block/CU; its serial LDS-burst -> MFMA-burst phases left both
// pipes ~45% idle).  Two co-resident blocks anti-phase: one block's MFMA burst
// overlaps the other's LDS burst (m114 co-scheduling mechanism).
// Schedule per phase p=2t+kh (region = kh, compile-time):
//   12 ds_read_b128 from R[kh] (round-6 swizzle, 0 conflicts)
//   stage phase p+1's K-half into R[1-kh] (dead since phase p-1's barrier)
//   lgkmcnt(0)+sched_barrier -> setprio(1) 32 MFMA setprio(0)
//   vmcnt(0) (stage issued mid-phase; drain covered by MFMA burst + other block)
//   s_barrier
// __launch_bounds__(512,4): 4 waves/SIMD = 2 blocks/CU, caps VGPR at 128
// (round-6 body = 104, fits).
// ---------------------------------------------------------------------------
#define FENCE() asm volatile("" ::: "memory")
#define BARRIER() do { FENCE(); __builtin_amdgcn_s_barrier(); FENCE(); } while (0)
#define WAIT_LGKM0() do { asm volatile("s_waitcnt lgkmcnt(0)" ::: "memory"); \
                          __builtin_amdgcn_sched_barrier(0); } while (0)

#define STAGEH(larr, Base, kh, t, r) do { if ((t) < nsteps) {                 \
    _Pragma("unroll")                                                         \
    for (int l_ = 0; l_ < 2; ++l_) {                                          \
        const int gi_ = (wave * 2 + l_) * 64 + lane;                          \
        const int rp_ = gi_ >> 3, sgi_ = gi_ & 7;                             \
        const int raw_ = sgi_ ^ (rp_ & 7);                                    \
        const int row_ = rp_ * 2 + (raw_ >> 2);                               \
        const int gk_ = raw_ & 3;                                             \
        const unsigned short* src_ = (Base) + (size_t)row_ * K                \
                  + ((size_t)(t) << 6) + (kh) * 32 + gk_ * 8;                 \
        unsigned short* dst_ = (unsigned short*)&(larr)[r][(wave * 2 + l_) * 512]; \
        __builtin_amdgcn_global_load_lds((AS1 const void*)src_,               \
                                         (AS3 void*)dst_, 16, 0, 0);          \
    } } } while (0)

// one phase: consume region R (literal 0/1), stage (ST, SKH) into region 1-R
#define PHASE2(R, ST, SKH) do {                                               \
    s16x8 a_[8], b_[4];                                                       \
    _Pragma("unroll")                                                         \
    for (int mf_ = 0; mf_ < 8; ++mf_) {                                       \
        const int row_ = wr * 128 + mf_ * 16 + (lane & 15);                   \
        const int raw_ = (row_ & 1) * 4 + (lane >> 4);                        \
        const int rp_ = row_ >> 1;                                            \
        a_[mf_] = *(const s16x8*)&lA[R][rp_ * 64 + ((raw_ ^ (rp_ & 7)) << 3)]; \
    }                                                                         \
    _Pragma("unroll")                                                         \
    for (int nf_ = 0; nf_ < 4; ++nf_) {                                       \
        const int row_ = wc * 64 + nf_ * 16 + (lane & 15);                    \
        const int raw_ = (row_ & 1) * 4 + (lane >> 4);                        \
        const int rp_ = row_ >> 1;                                            \
        b_[nf_] = *(const s16x8*)&lB[R][rp_ * 64 + ((raw_ ^ (rp_ & 7)) << 3)]; \
    }                                                                         \
    STAGEH(lA, Ab, SKH, ST, 1 - (R));                                         \
    STAGEH(lB, Wb, SKH, ST, 1 - (R));                                         \
    WAIT_LGKM0();                                                             \
    __builtin_amdgcn_s_setprio(1);                                            \
    _Pragma("unroll")                                                         \
    for (int mf_ = 0; mf_ < 8; ++mf_)                                         \
        _Pragma("unroll")                                                     \
        for (int nf_ = 0; nf_ < 4; ++nf_)                                     \
            acc[mf_][nf_] = __builtin_amdgcn_mfma_f32_16x16x32_bf16(          \
                a_[mf_], b_[nf_], acc[mf_][nf_], 0, 0, 0);                    \
    __builtin_amdgcn_s_setprio(0);                                            \
    asm volatile("s_waitcnt vmcnt(0)" ::: "memory");                          \
    BARRIER();                                                                \
} while (0)

__global__ __launch_bounds__(512, 4)
void gemm2p(const unsigned short* __restrict__ A, const unsigned short* __restrict__ W,
            unsigned short* __restrict__ C, int K) {
    const int cpx = gridDim.x >> 3;
    const int braw = blockIdx.x;
    const int bid = (braw & 7) * cpx + (braw >> 3);   // bijective: grid % 8 == 0
    const int mt = bid & 7;       // m-inner: W-panel L2 reuse
    const int nt = bid >> 3;
    const int tid = threadIdx.x;
    const int lane = tid & 63;
    const int wave = tid >> 6;
    const int wr = wave >> 2;     // 0..1
    const int wc = wave & 3;      // 0..3

    __shared__ unsigned short lA[2][8192];   // 2 regions: 256 rows x 32 k each
    __shared__ unsigned short lB[2][8192];   // total LDS = 64 KiB -> 2 blocks/CU

    f32x4 acc[8][4];
    #pragma unroll
    for (int m = 0; m < 8; ++m)
        #pragma unroll
        for (int n = 0; n < 4; ++n)
            acc[m][n] = (f32x4){0.f, 0.f, 0.f, 0.f};

    const unsigned short* Ab = A + (size_t)(mt * 256) * K;
    const unsigned short* Wb = W + (size_t)(nt * 256) * K;
    const int nsteps = K >> 6;

    // prologue: stage (t0, kh0) -> R0; drain; barrier
    STAGEH(lA, Ab, 0, 0, 0);
    STAGEH(lB, Wb, 0, 0, 0);
    asm volatile("s_waitcnt vmcnt(0)" ::: "memory");
    BARRIER();

    for (int t = 0; t < nsteps; ++t) {
        PHASE2(0, t, 1);         // consume R0 (t,kh0); stage (t,kh1) -> R1
        PHASE2(1, t + 1, 0);     // consume R1 (t,kh1); stage (t+1,kh0) -> R0
    }

    // epilogue: C/D layout col = lane&15, row = (lane>>4)*4 + reg
    const int colb = nt * 256 + wc * 64 + (lane & 15);
    const int rowb = mt * 256 + wr * 128 + ((lane >> 4) << 2);
    #pragma unroll
    for (int m = 0; m < 8; ++m)
        #pragma unroll
        for (int n = 0; n < 4; ++n) {
            #pragma unroll
            for (int j = 0; j < 4; ++j) {
                const size_t r = (size_t)(rowb + m * 16 + j);
                C[r * VOC + colb + n * 16] = f2bf(acc[m][n][j]);
            }
        }
}

// ---------------------------------------------------------------------------
// Fallback GEMM (fp32 operands, reg-staged convert) — used only if ws too small.
// ---------------------------------------------------------------------------
__global__ __launch_bounds__(256, 2)
void gemm_bf16(const float* __restrict__ A, const float* __restrict__ W,
               unsigned short* __restrict__ C, int K) {
    const int bid = blockIdx.x;
    const int mt = bid & 15;
    const int nt = bid >> 4;
    const int tid = threadIdx.x;
    const int lane = tid & 63;
    const int wave = tid >> 6;
    const int wm = (wave >> 1) << 6;
    const int wn = (wave & 1) << 6;

    __shared__ unsigned short lds[2][2][128 * 64];

    f32x4 acc[4][4];
    #pragma unroll
    for (int m = 0; m < 4; ++m)
        #pragma unroll
        for (int n = 0; n < 4; ++n)
            acc[m][n] = (f32x4){0.f, 0.f, 0.f, 0.f};

    const float* Ab = A + (size_t)(mt * 128) * K;
    const float* Wb = W + (size_t)(nt * 128) * K;
    const int nsteps = K >> 6;

    f32x4 ra[4][2], rb[4][2];
    int rrow[4], rk16[4];
    #pragma unroll
    for (int it = 0; it < 4; ++it) {
        int idx = it * 256 + tid;
        rrow[it] = idx >> 3;
        rk16[it] = idx & 7;
    }

    auto load_regs = [&](int step) {
        const int kb = step << 6;
        #pragma unroll
        for (int it = 0; it < 4; ++it) {
            const float* pa = Ab + (size_t)rrow[it] * K + kb + rk16[it] * 8;
            const float* pw = Wb + (size_t)rrow[it] * K + kb + rk16[it] * 8;
            ra[it][0] = *(const f32x4*)pa;
            ra[it][1] = *(const f32x4*)(pa + 4);
            rb[it][0] = *(const f32x4*)pw;
            rb[it][1] = *(const f32x4*)(pw + 4);
        }
    };

    auto write_lds = [&](int buf) {
        #pragma unroll
        for (int it = 0; it < 4; ++it) {
            const int row = rrow[it];
            const int sw = rk16[it] ^ (row & 7);
            const int off = row * 64 + sw * 8;
            u32x4 pa, pw;
            pa[0] = pk2(ra[it][0][0], ra[it][0][1]);
            pa[1] = pk2(ra[it][0][2], ra[it][0][3]);
            pa[2] = pk2(ra[it][1][0], ra[it][1][1]);
            pa[3] = pk2(ra[it][1][2], ra[it][1][3]);
            pw[0] = pk2(rb[it][0][0], rb[it][0][1]);
            pw[1] = pk2(rb[it][0][2], rb[it][0][3]);
            pw[2] = pk2(rb[it][1][0], rb[it][1][1]);
            pw[3] = pk2(rb[it][1][2], rb[it][1][3]);
            *(u32x4*)&lds[buf][0][off] = pa;
            *(u32x4*)&lds[buf][1][off] = pw;
        }
    };

    auto compute = [&](int buf) {
        #pragma unroll
        for (int ks = 0; ks < 2; ++ks) {
            const int g = ks * 4 + (lane >> 4);
            const int rsel = lane & 15;
            s16x8 afr[4], bwr[4];
            #pragma unroll
            for (int m = 0; m < 4; ++m) {
                int row = wm + m * 16 + rsel;
                afr[m] = *(const s16x8*)&lds[buf][0][row * 64 + ((g ^ (row & 7)) * 8)];
            }
            #pragma unroll
            for (int n = 0; n < 4; ++n) {
                int row = wn + n * 16 + rsel;
                bwr[n] = *(const s16x8*)&lds[buf][1][row * 64 + ((g ^ (row & 7)) * 8)];
            }
            #pragma unroll
            for (int m = 0; m < 4; ++m)
                #pragma unroll
                for (int n = 0; n < 4; ++n)
                    acc[m][n] = __builtin_amdgcn_mfma_f32_16x16x32_bf16(
                        afr[m], bwr[n], acc[m][n], 0, 0, 0);
        }
    };

    load_regs(0);
    write_lds(0);
    __syncthreads();
    for (int s = 0; s < nsteps; ++s) {
        if (s + 1 < nsteps) load_regs(s + 1);
        compute(s & 1);
        if (s + 1 < nsteps) write_lds((s + 1) & 1);
        __syncthreads();
    }

    const int colb = nt * 128 + wn + (lane & 15);
    const int rowb = mt * 128 + wm + ((lane >> 4) << 2);
    #pragma unroll
    for (int m = 0; m < 4; ++m)
        #pragma unroll
        for (int n = 0; n < 4; ++n) {
            #pragma unroll
            for (int j = 0; j < 4; ++j) {
                int r = rowb + m * 16 + j;
                int c = colb + n * 16;
                C[(size_t)r * VOC + c] = f2bf(acc[m][n][j]);
            }
        }
}

// ---------------------------------------------------------------------------
// count kernel: n_non_ignore -> 1/n (or 0), and zero d_out (graph-replay safe)
// ---------------------------------------------------------------------------
__global__ void count_kernel(const int* __restrict__ label,
                             float* __restrict__ invn, float* __restrict__ out) {
    int tid = threadIdx.x;
    int c = 0;
    for (int i = tid; i < BT; i += 256) c += (label[i] != IGN) ? 1 : 0;
    #pragma unroll
    for (int o = 32; o > 0; o >>= 1) c += __shfl_xor(c, o);
    __shared__ int red[4];
    if ((tid & 63) == 0) red[tid >> 6] = c;
    __syncthreads();
    if (tid == 0) {
        int n = red[0] + red[1] + red[2] + red[3];
        invn[0] = (n > 0) ? (1.0f / (float)n) : 0.0f;
        out[0] = 0.0f;
    }
}

// ---------------------------------------------------------------------------
// JSD kernel: one block per token, 2 passes over both bf16 logit rows.
// Pass 1: online max+sumexp -> lse.  Pass 2: JSD terms -> atomicAdd.
// ---------------------------------------------------------------------------
__global__ __launch_bounds__(1024)
void jsd_kernel(const unsigned short* __restrict__ TL, const unsigned short* __restrict__ SL,
                const int* __restrict__ label, const float* __restrict__ invn,
                float* __restrict__ out) {
    const int b = blockIdx.x;
    const int tid = threadIdx.x;
    const unsigned short* tl = TL + (size_t)b * VOC;
    const unsigned short* sl = SL + (size_t)b * VOC;
    __shared__ float rmA[16], rsA[16], rmB[16], rsB[16];
    __shared__ float lse2[2];

    float mp = -3.0e38f, sp = 0.f, mq = -3.0e38f, sq = 0.f;
    for (int i = tid; i < VOC / 8; i += 1024) {
        s16x8 vt = *(const s16x8*)(tl + i * 8);
        s16x8 vs = *(const s16x8*)(sl + i * 8);
        #pragma unroll
        for (int j = 0; j < 8; ++j) {
            float x = bf2f((unsigned short)vt[j]);
            if (x > mp) { sp = sp * __expf(mp - x) + 1.0f; mp = x; }
            else        { sp += __expf(x - mp); }
            float y = bf2f((unsigned short)vs[j]);
            if (y > mq) { sq = sq * __expf(mq - y) + 1.0f; mq = y; }
            else        { sq += __expf(y - mq); }
        }
    }
    #pragma unroll
    for (int o = 32; o > 0; o >>= 1) {
        float om = __shfl_xor(mp, o), os = __shfl_xor(sp, o);
        float nm = fmaxf(mp, om);
        sp = sp * __expf(mp - nm) + os * __expf(om - nm);
        mp = nm;
        om = __shfl_xor(mq, o); os = __shfl_xor(sq, o);
        nm = fmaxf(mq, om);
        sq = sq * __expf(mq - nm) + os * __expf(om - nm);
        mq = nm;
    }
    if ((tid & 63) == 0) {
        rmA[tid >> 6] = mp; rsA[tid >> 6] = sp;
        rmB[tid >> 6] = mq; rsB[tid >> 6] = sq;
    }
    __syncthreads();
    if (tid == 0) {
        float m1 = rmA[0], s1 = 0.f, m2 = rmB[0], s2 = 0.f;
        for (int w = 1; w < 16; ++w) { m1 = fmaxf(m1, rmA[w]); m2 = fmaxf(m2, rmB[w]); }
        for (int w = 0; w < 16; ++w) {
            s1 += rsA[w] * __expf(rmA[w] - m1);
            s2 += rsB[w] * __expf(rmB[w] - m2);
        }
        lse2[0] = m1 + __logf(s1);
        lse2[1] = m2 + __logf(s2);
    }
    __syncthreads();
    const float lsep = lse2[0];
    const float lseq = lse2[1];

    float accj = 0.f;
    for (int i = tid; i < VOC / 8; i += 1024) {
        s16x8 vt = *(const s16x8*)(tl + i * 8);
        s16x8 vs = *(const s16x8*)(sl + i * 8);
        #pragma unroll
        for (int j = 0; j < 8; ++j) {
            float lp = bf2f((unsigned short)vt[j]) - lsep;
            float lq = bf2f((unsigned short)vs[j]) - lseq;
            float m0 = fmaxf(lp, lq);
            float e = __expf(-fabsf(lp - lq));
            float lm = m0 + __logf(0.5f * (1.0f + e));
            accj += 0.5f * (__expf(lp) * (lp - lm) + __expf(lq) * (lq - lm));
        }
    }
    #pragma unroll
    for (int o = 32; o > 0; o >>= 1) accj += __shfl_xor(accj, o);
    if ((tid & 63) == 0) rmA[tid >> 6] = accj;
    __syncthreads();
    if (tid == 0) {
        float a = 0.f;
        for (int w = 0; w < 16; ++w) a += rmA[w];
        if (label[b] != IGN) atomicAdd(out, a * invn[0]);
    }
}

extern "C" void kernel_launch(void* const* d_in, const int* in_sizes, int n_in,
                              void* d_out, int out_size, void* d_ws, size_t ws_size,
                              hipStream_t stream) {
    const float* s_in = (const float*)d_in[0];   // [BT, 2048]
    const float* t_in = (const float*)d_in[1];   // [BT, 4096]
    const float* Ws   = (const float*)d_in[2];   // [VOC, 2048]
    const float* Wt   = (const float*)d_in[3];   // [VOC, 4096]
    const int* label  = (const int*)d_in[4];     // [BT]
    float* out = (float*)d_out;

    const size_t L   = (size_t)BT * VOC;
    const size_t eWt = (size_t)VOC * 4096;
    const size_t eWs = (size_t)VOC * 2048;
    const size_t eAt = (size_t)BT * 4096;
    const size_t eAs = (size_t)BT * 2048;

    const size_t need_full = (2 * L + eWt + eWs + eAt + eAs) * sizeof(unsigned short) + 64;
    const size_t need_min  = 2 * L * sizeof(unsigned short) + 64;

    if (ws_size >= need_full) {
        unsigned short* logT = (unsigned short*)d_ws;
        unsigned short* logS = logT + L;
        unsigned short* Wtb  = logS + L;
        unsigned short* Wsb  = Wtb + eWt;
        unsigned short* Atb  = Wsb + eWs;
        unsigned short* Asb  = Atb + eAt;
        float* invn = (float*)(Asb + eAs);

        cvt_kernel<<<dim3(2048), dim3(256), 0, stream>>>(Wt, Wtb, (int)(eWt / 8));
        cvt_kernel<<<dim3(2048), dim3(256), 0, stream>>>(Ws, Wsb, (int)(eWs / 8));
        cvt_kernel<<<dim3(1024), dim3(256), 0, stream>>>(t_in, Atb, (int)(eAt / 8));
        cvt_kernel<<<dim3(1024), dim3(256), 0, stream>>>(s_in, Asb, (int)(eAs / 8));
        count_kernel<<<dim3(1), dim3(256), 0, stream>>>(label, invn, out);
        gemm2p<<<dim3(8 * (VOC / 256)), dim3(512), 0, stream>>>(Atb, Wtb, logT, 4096);
        gemm2p<<<dim3(8 * (VOC / 256)), dim3(512), 0, stream>>>(Asb, Wsb, logS, 2048);
        jsd_kernel<<<dim3(BT), dim3(1024), 0, stream>>>(logT, logS, label, invn, out);
    } else {
        if (ws_size < need_min) return;
        unsigned short* logT = (unsigned short*)d_ws;
        unsigned short* logS = logT + L;
        float* invn = (float*)(logS + L);

        count_kernel<<<dim3(1), dim3(256), 0, stream>>>(label, invn, out);
        gemm_bf16<<<dim3(16 * (VOC / 128)), dim3(256), 0, stream>>>(t_in, Wt, logT, 4096);
        gemm_bf16<<<dim3(16 * (VOC / 128)), dim3(256), 0, stream>>>(s_in, Ws, logS, 2048);
        jsd_kernel<<<dim3(BT), dim3(1024), 0, stream>>>(logT, logS, label, invn, out);
    }
}

// Round 11
// 1240.271 us; speedup vs baseline: 6.8256x; 6.8256x over previous
//
#include <hip/hip_runtime.h>
#include <hip/hip_bf16.h>

#define BT 2048
#define VOC 32000
#define IGN (-100)

typedef __attribute__((ext_vector_type(4))) float f32x4;
typedef __attribute__((ext_vector_type(8))) short s16x8;
typedef __attribute__((ext_vector_type(4))) unsigned int u32x4;

#define AS1 __attribute__((address_space(1)))
#define AS3 __attribute__((address_space(3)))

__device__ __forceinline__ unsigned short f2bf(float f) {
    union { __hip_bfloat16 h; unsigned short u; } c;
    c.h = __float2bfloat16(f);
    return c.u;
}
__device__ __forceinline__ float bf2f(unsigned short u) {
    union { unsigned int u; float f; } c;
    c.u = ((unsigned int)u) << 16;
    return c.f;
}
__device__ __forceinline__ unsigned int pk2(float a, float b) {
    return (unsigned int)f2bf(a) | ((unsigned int)f2bf(b) << 16);
}

// ---------------------------------------------------------------------------
// fp32 -> bf16 pre-convert, row-major
// ---------------------------------------------------------------------------
__global__ __launch_bounds__(256)
void cvt_kernel(const float* __restrict__ in, unsigned short* __restrict__ out, int n8) {
    for (int i = blockIdx.x * 256 + threadIdx.x; i < n8; i += gridDim.x * 256) {
        f32x4 a = ((const f32x4*)in)[2 * i];
        f32x4 b = ((const f32x4*)in)[2 * i + 1];
        u32x4 o;
        o[0] = pk2(a[0], a[1]);
        o[1] = pk2(a[2], a[3]);
        o[2] = pk2(b[0], b[1]);
        o[3] = pk2(b[2], b[3]);
        ((u32x4*)out)[i] = o;
    }
}

// ---------------------------------------------------------------------------
// 256x256 GEMM (bf16 operands), 4-region K-half ring, ONE barrier per K-tile.
// C[m,v] = sum_k A[m,k] * W[v,k].  BK=64 = 2 K-halves (one 16x16x32 step each).
// 512 thr (8 waves 2Mx4N), per-wave 128x64 out.  LDS 128 KiB -> 1 block/CU
// (register-forced anyway: acc=128 f32/lane caps us at 2 waves/SIMD).
//
// vs round 6 (proven 518us teacher): the mid-tile barrier is REMOVED.
// Per K-tile t (regions: even tiles R0/R1, odd tiles R2/R3):
//   issue 8 stage-gloads for tile t+1 into the OTHER region pair
//     (pair consumed at t-1; dead since barrier(t-1) -> WAR-safe)
//   12 ds_read (kh0) -> lgkmcnt(0)+sched_barrier -> setprio(1) 32 MFMA
//   12 ds_read (kh1) -> lgkmcnt(0)+sched_barrier -> setprio(1) 32 MFMA
//   vmcnt(0)  (stages issued ~3000cyc earlier -> wait ~free)
//   s_barrier (single lockstep point per tile)
// Mechanism: one less reconvergence per tile; kh1's LDS service overlaps
// other waves' kh0 MFMA (no barrier in between).  Register peak ~170
// (12 frags live at a time, not 24).
// ---------------------------------------------------------------------------
#define FENCE() asm volatile("" ::: "memory")
#define BARRIER() do { FENCE(); __builtin_amdgcn_s_barrier(); FENCE(); } while (0)
#define WAIT_LGKM0() do { asm volatile("s_waitcnt lgkmcnt(0)" ::: "memory"); \
                          __builtin_amdgcn_sched_barrier(0); } while (0)

#define STAGEH(larr, Base, kh, t, r) do { if ((t) < nsteps) {                 \
    _Pragma("unroll")                                                         \
    for (int l_ = 0; l_ < 2; ++l_) {                                          \
        const int gi_ = (wave * 2 + l_) * 64 + lane;                          \
        const int rp_ = gi_ >> 3, sgi_ = gi_ & 7;                             \
        const int raw_ = sgi_ ^ (rp_ & 7);                                    \
        const int row_ = rp_ * 2 + (raw_ >> 2);                               \
        const int gk_ = raw_ & 3;                                             \
        const unsigned short* src_ = (Base) + (size_t)row_ * K                \
                  + ((size_t)(t) << 6) + (kh) * 32 + gk_ * 8;                 \
        unsigned short* dst_ = (unsigned short*)&(larr)[r][(wave * 2 + l_) * 512]; \
        __builtin_amdgcn_global_load_lds((AS1 const void*)src_,               \
                                         (AS3 void*)dst_, 16, 0, 0);          \
    } } } while (0)

// consume one K-half from region R (compile-time); no barrier here
#define HALF(R) do {                                                          \
    s16x8 a_[8], b_[4];                                                       \
    _Pragma("unroll")                                                         \
    for (int mf_ = 0; mf_ < 8; ++mf_) {                                       \
        const int row_ = wr * 128 + mf_ * 16 + (lane & 15);                   \
        const int raw_ = (row_ & 1) * 4 + (lane >> 4);                        \
        const int rp_ = row_ >> 1;                                            \
        a_[mf_] = *(const s16x8*)&lA[R][rp_ * 64 + ((raw_ ^ (rp_ & 7)) << 3)]; \
    }                                                                         \
    _Pragma("unroll")                                                         \
    for (int nf_ = 0; nf_ < 4; ++nf_) {                                       \
        const int row_ = wc * 64 + nf_ * 16 + (lane & 15);                    \
        const int raw_ = (row_ & 1) * 4 + (lane >> 4);                        \
        const int rp_ = row_ >> 1;                                            \
        b_[nf_] = *(const s16x8*)&lB[R][rp_ * 64 + ((raw_ ^ (rp_ & 7)) << 3)]; \
    }                                                                         \
    WAIT_LGKM0();                                                             \
    __builtin_amdgcn_s_setprio(1);                                            \
    _Pragma("unroll")                                                         \
    for (int mf_ = 0; mf_ < 8; ++mf_)                                         \
        _Pragma("unroll")                                                     \
        for (int nf_ = 0; nf_ < 4; ++nf_)                                     \
            acc[mf_][nf_] = __builtin_amdgcn_mfma_f32_16x16x32_bf16(          \
                a_[mf_], b_[nf_], acc[mf_][nf_], 0, 0, 0);                    \
    __builtin_amdgcn_s_setprio(0);                                            \
} while (0)

__global__ __launch_bounds__(512, 2)
void gemm2p(const unsigned short* __restrict__ A, const unsigned short* __restrict__ W,
            unsigned short* __restrict__ C, int K) {
    const int cpx = gridDim.x >> 3;
    const int braw = blockIdx.x;
    const int bid = (braw & 7) * cpx + (braw >> 3);   // bijective: grid % 8 == 0
    const int mt = bid & 7;       // m-inner: W-panel L2 reuse
    const int nt = bid >> 3;
    const int tid = threadIdx.x;
    const int lane = tid & 63;
    const int wave = tid >> 6;
    const int wr = wave >> 2;     // 0..1
    const int wc = wave & 3;      // 0..3

    __shared__ unsigned short lA[4][8192];   // 4 regions: 256 rows x 32 k each
    __shared__ unsigned short lB[4][8192];

    f32x4 acc[8][4];
    #pragma unroll
    for (int m = 0; m < 8; ++m)
        #pragma unroll
        for (int n = 0; n < 4; ++n)
            acc[m][n] = (f32x4){0.f, 0.f, 0.f, 0.f};

    const unsigned short* Ab = A + (size_t)(mt * 256) * K;
    const unsigned short* Wb = W + (size_t)(nt * 256) * K;
    const int nsteps = K >> 6;

    // prologue: stage tile0 (kh0->R0, kh1->R1); drain; barrier
    STAGEH(lA, Ab, 0, 0, 0); STAGEH(lB, Wb, 0, 0, 0);
    STAGEH(lA, Ab, 1, 0, 1); STAGEH(lB, Wb, 1, 0, 1);
    asm volatile("s_waitcnt vmcnt(0)" ::: "memory");
    BARRIER();

    for (int t = 0; t < nsteps; t += 2) {     // nsteps even (32 or 64)
        // tile t (even): consume R0,R1; stage tile t+1 -> R2,R3 (dead since t-1)
        STAGEH(lA, Ab, 0, t + 1, 2); STAGEH(lB, Wb, 0, t + 1, 2);
        STAGEH(lA, Ab, 1, t + 1, 3); STAGEH(lB, Wb, 1, t + 1, 3);
        HALF(0);
        HALF(1);
        asm volatile("s_waitcnt vmcnt(0)" ::: "memory");
        BARRIER();
        // tile t+1 (odd): consume R2,R3; stage tile t+2 -> R0,R1
        STAGEH(lA, Ab, 0, t + 2, 0); STAGEH(lB, Wb, 0, t + 2, 0);
        STAGEH(lA, Ab, 1, t + 2, 1); STAGEH(lB, Wb, 1, t + 2, 1);
        HALF(2);
        HALF(3);
        asm volatile("s_waitcnt vmcnt(0)" ::: "memory");
        BARRIER();
    }

    // epilogue: C/D layout col = lane&15, row = (lane>>4)*4 + reg
    const int colb = nt * 256 + wc * 64 + (lane & 15);
    const int rowb = mt * 256 + wr * 128 + ((lane >> 4) << 2);
    #pragma unroll
    for (int m = 0; m < 8; ++m)
        #pragma unroll
        for (int n = 0; n < 4; ++n) {
            #pragma unroll
            for (int j = 0; j < 4; ++j) {
                const size_t r = (size_t)(rowb + m * 16 + j);
                C[r * VOC + colb + n * 16] = f2bf(acc[m][n][j]);
            }
        }
}

// ---------------------------------------------------------------------------
// Fallback GEMM (fp32 operands, reg-staged convert) — used only if ws too small.
// ---------------------------------------------------------------------------
__global__ __launch_bounds__(256, 2)
void gemm_bf16(const float* __restrict__ A, const float* __restrict__ W,
               unsigned short* __restrict__ C, int K) {
    const int bid = blockIdx.x;
    const int mt = bid & 15;
    const int nt = bid >> 4;
    const int tid = threadIdx.x;
    const int lane = tid & 63;
    const int wave = tid >> 6;
    const int wm = (wave >> 1) << 6;
    const int wn = (wave & 1) << 6;

    __shared__ unsigned short lds[2][2][128 * 64];

    f32x4 acc[4][4];
    #pragma unroll
    for (int m = 0; m < 4; ++m)
        #pragma unroll
        for (int n = 0; n < 4; ++n)
            acc[m][n] = (f32x4){0.f, 0.f, 0.f, 0.f};

    const float* Ab = A + (size_t)(mt * 128) * K;
    const float* Wb = W + (size_t)(nt * 128) * K;
    const int nsteps = K >> 6;

    f32x4 ra[4][2], rb[4][2];
    int rrow[4], rk16[4];
    #pragma unroll
    for (int it = 0; it < 4; ++it) {
        int idx = it * 256 + tid;
        rrow[it] = idx >> 3;
        rk16[it] = idx & 7;
    }

    auto load_regs = [&](int step) {
        const int kb = step << 6;
        #pragma unroll
        for (int it = 0; it < 4; ++it) {
            const float* pa = Ab + (size_t)rrow[it] * K + kb + rk16[it] * 8;
            const float* pw = Wb + (size_t)rrow[it] * K + kb + rk16[it] * 8;
            ra[it][0] = *(const f32x4*)pa;
            ra[it][1] = *(const f32x4*)(pa + 4);
            rb[it][0] = *(const f32x4*)pw;
            rb[it][1] = *(const f32x4*)(pw + 4);
        }
    };

    auto write_lds = [&](int buf) {
        #pragma unroll
        for (int it = 0; it < 4; ++it) {
            const int row = rrow[it];
            const int sw = rk16[it] ^ (row & 7);
            const int off = row * 64 + sw * 8;
            u32x4 pa, pw;
            pa[0] = pk2(ra[it][0][0], ra[it][0][1]);
            pa[1] = pk2(ra[it][0][2], ra[it][0][3]);
            pa[2] = pk2(ra[it][1][0], ra[it][1][1]);
            pa[3] = pk2(ra[it][1][2], ra[it][1][3]);
            pw[0] = pk2(rb[it][0][0], rb[it][0][1]);
            pw[1] = pk2(rb[it][0][2], rb[it][0][3]);
            pw[2] = pk2(rb[it][1][0], rb[it][1][1]);
            pw[3] = pk2(rb[it][1][2], rb[it][1][3]);
            *(u32x4*)&lds[buf][0][off] = pa;
            *(u32x4*)&lds[buf][1][off] = pw;
        }
    };

    auto compute = [&](int buf) {
        #pragma unroll
        for (int ks = 0; ks < 2; ++ks) {
            const int g = ks * 4 + (lane >> 4);
            const int rsel = lane & 15;
            s16x8 afr[4], bwr[4];
            #pragma unroll
            for (int m = 0; m < 4; ++m) {
                int row = wm + m * 16 + rsel;
                afr[m] = *(const s16x8*)&lds[buf][0][row * 64 + ((g ^ (row & 7)) * 8)];
            }
            #pragma unroll
            for (int n = 0; n < 4; ++n) {
                int row = wn + n * 16 + rsel;
                bwr[n] = *(const s16x8*)&lds[buf][1][row * 64 + ((g ^ (row & 7)) * 8)];
            }
            #pragma unroll
            for (int m = 0; m < 4; ++m)
                #pragma unroll
                for (int n = 0; n < 4; ++n)
                    acc[m][n] = __builtin_amdgcn_mfma_f32_16x16x32_bf16(
                        afr[m], bwr[n], acc[m][n], 0, 0, 0);
        }
    };

    load_regs(0);
    write_lds(0);
    __syncthreads();
    for (int s = 0; s < nsteps; ++s) {
        if (s + 1 < nsteps) load_regs(s + 1);
        compute(s & 1);
        if (s + 1 < nsteps) write_lds((s + 1) & 1);
        __syncthreads();
    }

    const int colb = nt * 128 + wn + (lane & 15);
    const int rowb = mt * 128 + wm + ((lane >> 4) << 2);
    #pragma unroll
    for (int m = 0; m < 4; ++m)
        #pragma unroll
        for (int n = 0; n < 4; ++n) {
            #pragma unroll
            for (int j = 0; j < 4; ++j) {
                int r = rowb + m * 16 + j;
                int c = colb + n * 16;
                C[(size_t)r * VOC + c] = f2bf(acc[m][n][j]);
            }
        }
}

// ---------------------------------------------------------------------------
// count kernel: n_non_ignore -> 1/n (or 0), and zero d_out (graph-replay safe)
// ---------------------------------------------------------------------------
__global__ void count_kernel(const int* __restrict__ label,
                             float* __restrict__ invn, float* __restrict__ out) {
    int tid = threadIdx.x;
    int c = 0;
    for (int i = tid; i < BT; i += 256) c += (label[i] != IGN) ? 1 : 0;
    #pragma unroll
    for (int o = 32; o > 0; o >>= 1) c += __shfl_xor(c, o);
    __shared__ int red[4];
    if ((tid & 63) == 0) red[tid >> 6] = c;
    __syncthreads();
    if (tid == 0) {
        int n = red[0] + red[1] + red[2] + red[3];
        invn[0] = (n > 0) ? (1.0f / (float)n) : 0.0f;
        out[0] = 0.0f;
    }
}

// ---------------------------------------------------------------------------
// JSD kernel: one block per token, 2 passes over both bf16 logit rows.
// Pass 1: online max+sumexp -> lse.  Pass 2: JSD terms -> atomicAdd.
// ---------------------------------------------------------------------------
__global__ __launch_bounds__(1024)
void jsd_kernel(const unsigned short* __restrict__ TL, const unsigned short* __restrict__ SL,
                const int* __restrict__ label, const float* __restrict__ invn,
                float* __restrict__ out) {
    const int b = blockIdx.x;
    const int tid = threadIdx.x;
    const unsigned short* tl = TL + (size_t)b * VOC;
    const unsigned short* sl = SL + (size_t)b * VOC;
    __shared__ float rmA[16], rsA[16], rmB[16], rsB[16];
    __shared__ float lse2[2];

    float mp = -3.0e38f, sp = 0.f, mq = -3.0e38f, sq = 0.f;
    for (int i = tid; i < VOC / 8; i += 1024) {
        s16x8 vt = *(const s16x8*)(tl + i * 8);
        s16x8 vs = *(const s16x8*)(sl + i * 8);
        #pragma unroll
        for (int j = 0; j < 8; ++j) {
            float x = bf2f((unsigned short)vt[j]);
            if (x > mp) { sp = sp * __expf(mp - x) + 1.0f; mp = x; }
            else        { sp += __expf(x - mp); }
            float y = bf2f((unsigned short)vs[j]);
            if (y > mq) { sq = sq * __expf(mq - y) + 1.0f; mq = y; }
            else        { sq += __expf(y - mq); }
        }
    }
    #pragma unroll
    for (int o = 32; o > 0; o >>= 1) {
        float om = __shfl_xor(mp, o), os = __shfl_xor(sp, o);
        float nm = fmaxf(mp, om);
        sp = sp * __expf(mp - nm) + os * __expf(om - nm);
        mp = nm;
        om = __shfl_xor(mq, o); os = __shfl_xor(sq, o);
        nm = fmaxf(mq, om);
        sq = sq * __expf(mq - nm) + os * __expf(om - nm);
        mq = nm;
    }
    if ((tid & 63) == 0) {
        rmA[tid >> 6] = mp; rsA[tid >> 6] = sp;
        rmB[tid >> 6] = mq; rsB[tid >> 6] = sq;
    }
    __syncthreads();
    if (tid == 0) {
        float m1 = rmA[0], s1 = 0.f, m2 = rmB[0], s2 = 0.f;
        for (int w = 1; w < 16; ++w) { m1 = fmaxf(m1, rmA[w]); m2 = fmaxf(m2, rmB[w]); }
        for (int w = 0; w < 16; ++w) {
            s1 += rsA[w] * __expf(rmA[w] - m1);
            s2 += rsB[w] * __expf(rmB[w] - m2);
        }
        lse2[0] = m1 + __logf(s1);
        lse2[1] = m2 + __logf(s2);
    }
    __syncthreads();
    const float lsep = lse2[0];
    const float lseq = lse2[1];

    float accj = 0.f;
    for (int i = tid; i < VOC / 8; i += 1024) {
        s16x8 vt = *(const s16x8*)(tl + i * 8);
        s16x8 vs = *(const s16x8*)(sl + i * 8);
        #pragma unroll
        for (int j = 0; j < 8; ++j) {
            float lp = bf2f((unsigned short)vt[j]) - lsep;
            float lq = bf2f((unsigned short)vs[j]) - lseq;
            float m0 = fmaxf(lp, lq);
            float e = __expf(-fabsf(lp - lq));
            float lm = m0 + __logf(0.5f * (1.0f + e));
            accj += 0.5f * (__expf(lp) * (lp - lm) + __expf(lq) * (lq - lm));
        }
    }
    #pragma unroll
    for (int o = 32; o > 0; o >>= 1) accj += __shfl_xor(accj, o);
    if ((tid & 63) == 0) rmA[tid >> 6] = accj;
    __syncthreads();
    if (tid == 0) {
        float a = 0.f;
        for (int w = 0; w < 16; ++w) a += rmA[w];
        if (label[b] != IGN) atomicAdd(out, a * invn[0]);
    }
}

extern "C" void kernel_launch(void* const* d_in, const int* in_sizes, int n_in,
                              void* d_out, int out_size, void* d_ws, size_t ws_size,
                              hipStream_t stream) {
    const float* s_in = (const float*)d_in[0];   // [BT, 2048]
    const float* t_in = (const float*)d_in[1];   // [BT, 4096]
    const float* Ws   = (const float*)d_in[2];   // [VOC, 2048]
    const float* Wt   = (const float*)d_in[3];   // [VOC, 4096]
    const int* label  = (const int*)d_in[4];     // [BT]
    float* out = (float*)d_out;

    const size_t L   = (size_t)BT * VOC;
    const size_t eWt = (size_t)VOC * 4096;
    const size_t eWs = (size_t)VOC * 2048;
    const size_t eAt = (size_t)BT * 4096;
    const size_t eAs = (size_t)BT * 2048;

    const size_t need_full = (2 * L + eWt + eWs + eAt + eAs) * sizeof(unsigned short) + 64;
    const size_t need_min  = 2 * L * sizeof(unsigned short) + 64;

    if (ws_size >= need_full) {
        unsigned short* logT = (unsigned short*)d_ws;
        unsigned short* logS = logT + L;
        unsigned short* Wtb  = logS + L;
        unsigned short* Wsb  = Wtb + eWt;
        unsigned short* Atb  = Wsb + eWs;
        unsigned short* Asb  = Atb + eAt;
        float* invn = (float*)(Asb + eAs);

        cvt_kernel<<<dim3(2048), dim3(256), 0, stream>>>(Wt, Wtb, (int)(eWt / 8));
        cvt_kernel<<<dim3(2048), dim3(256), 0, stream>>>(Ws, Wsb, (int)(eWs / 8));
        cvt_kernel<<<dim3(1024), dim3(256), 0, stream>>>(t_in, Atb, (int)(eAt / 8));
        cvt_kernel<<<dim3(1024), dim3(256), 0, stream>>>(s_in, Asb, (int)(eAs / 8));
        count_kernel<<<dim3(1), dim3(256), 0, stream>>>(label, invn, out);
        gemm2p<<<dim3(8 * (VOC / 256)), dim3(512), 0, stream>>>(Atb, Wtb, logT, 4096);
        gemm2p<<<dim3(8 * (VOC / 256)), dim3(512), 0, stream>>>(Asb, Wsb, logS, 2048);
        jsd_kernel<<<dim3(BT), dim3(1024), 0, stream>>>(logT, logS, label, invn, out);
    } else {
        if (ws_size < need_min) return;
        unsigned short* logT = (unsigned short*)d_ws;
        unsigned short* logS = logT + L;
        float* invn = (float*)(logS + L);

        count_kernel<<<dim3(1), dim3(256), 0, stream>>>(label, invn, out);
        gemm_bf16<<<dim3(16 * (VOC / 128)), dim3(256), 0, stream>>>(t_in, Wt, logT, 4096);
        gemm_bf16<<<dim3(16 * (VOC / 128)), dim3(256), 0, stream>>>(s_in, Ws, logS, 2048);
        jsd_kernel<<<dim3(BT), dim3(1024), 0, stream>>>(logT, logS, label, invn, out);
    }
}

// Round 12
// 1107.449 us; speedup vs baseline: 7.6442x; 1.1199x over previous
//
#include <hip/hip_runtime.h>
#include <hip/hip_bf16.h>

#define BT 2048
#define VOC 32000
#define IGN (-100)

typedef __attribute__((ext_vector_type(4))) float f32x4;
typedef __attribute__((ext_vector_type(16))) float f32x16;
typedef __attribute__((ext_vector_type(8))) short s16x8;
typedef __attribute__((ext_vector_type(4))) unsigned int u32x4;

#define AS1 __attribute__((address_space(1)))
#define AS3 __attribute__((address_space(3)))

__device__ __forceinline__ unsigned short f2bf(float f) {
    union { __hip_bfloat16 h; unsigned short u; } c;
    c.h = __float2bfloat16(f);
    return c.u;
}
__device__ __forceinline__ float bf2f(unsigned short u) {
    union { unsigned int u; float f; } c;
    c.u = ((unsigned int)u) << 16;
    return c.f;
}
__device__ __forceinline__ unsigned int pk2(float a, float b) {
    return (unsigned int)f2bf(a) | ((unsigned int)f2bf(b) << 16);
}

// ---------------------------------------------------------------------------
// fp32 -> bf16 pre-convert, row-major
// ---------------------------------------------------------------------------
__global__ __launch_bounds__(256)
void cvt_kernel(const float* __restrict__ in, unsigned short* __restrict__ out, int n8) {
    for (int i = blockIdx.x * 256 + threadIdx.x; i < n8; i += gridDim.x * 256) {
        f32x4 a = ((const f32x4*)in)[2 * i];
        f32x4 b = ((const f32x4*)in)[2 * i + 1];
        u32x4 o;
        o[0] = pk2(a[0], a[1]);
        o[1] = pk2(a[2], a[3]);
        o[2] = pk2(b[0], b[1]);
        o[3] = pk2(b[2], b[3]);
        ((u32x4*)out)[i] = o;
    }
}

// ---------------------------------------------------------------------------
// 256x256 GEMM (bf16), mfma_f32_32x32x16, K=16 substep software pipeline.
// 512 thr (8 waves 2Mx4N), per-wave 128x64 out = 4x2 blocks of 32x32,
// acc = 8 x f32x16 = 128 regs.  LDS: same 4-region K-half ring + swizzle +
// global_load_lds staging as round 6 (layout/staging macros unchanged).
//
// Phase p (region p%4, K=32) = substeps s0 (k0-15), s1 (k16-31), 6 reads each
// (4 A + 2 B).  Body(p), between barriers:
//   R(p,s0)[6]  STG(p+2->region (p+2)%4)  L6  M(p-1,s1)   <- overlap
//   R(p,s1)[6]                            L6  M(p,s0)     <- overlap
//   vmcnt(4) [or 0 at tail]  barrier
// lgkmcnt(6) waits only the older 6-read batch -> the newer batch's LDS
// service overlaps the MFMA burst.  Live frags = 2 sets x 24 regs = 48
// (same as round 6's single set -> no register growth, ~232/256 total).
// Ring safety: STG(p+2) targets region (p-2)%4 whose reads completed before
// barrier_{p-1} (their L6 precedes it); landed via vmcnt(4) one phase before
// use; last two bodies use vmcnt(0) since their stages are skipped.
// A/B operand layout (32x32x16): row/col = lane&31, k = (lane>>5)*8 + j.
// C/D layout (HW-verified): col = lane&31, row = (reg&3)+8*(reg>>2)+4*(lane>>5).
// ---------------------------------------------------------------------------
#define FENCE() asm volatile("" ::: "memory")
#define BARRIER() do { FENCE(); __builtin_amdgcn_s_barrier(); FENCE(); } while (0)
#define VM4() asm volatile("s_waitcnt vmcnt(4)" ::: "memory")
#define VM0() asm volatile("s_waitcnt vmcnt(0)" ::: "memory")
#define L6() do { __builtin_amdgcn_sched_barrier(0); \
                  asm volatile("s_waitcnt lgkmcnt(6)" ::: "memory"); \
                  __builtin_amdgcn_sched_barrier(0); } while (0)
#define L0() do { __builtin_amdgcn_sched_barrier(0); \
                  asm volatile("s_waitcnt lgkmcnt(0)" ::: "memory"); \
                  __builtin_amdgcn_sched_barrier(0); } while (0)

#define STAGEH(larr, Base, kh, t, r) do { if ((t) < nsteps) {                 \
    _Pragma("unroll")                                                         \
    for (int l_ = 0; l_ < 2; ++l_) {                                          \
        const int gi_ = (wave * 2 + l_) * 64 + lane;                          \
        const int rp_ = gi_ >> 3, sgi_ = gi_ & 7;                             \
        const int raw_ = sgi_ ^ (rp_ & 7);                                    \
        const int row_ = rp_ * 2 + (raw_ >> 2);                               \
        const int gk_ = raw_ & 3;                                             \
        const unsigned short* src_ = (Base) + (size_t)row_ * K                \
                  + ((size_t)(t) << 6) + (kh) * 32 + gk_ * 8;                 \
        unsigned short* dst_ = (unsigned short*)&(larr)[r][(wave * 2 + l_) * 512]; \
        __builtin_amdgcn_global_load_lds((AS1 const void*)src_,               \
                                         (AS3 void*)dst_, 16, 0, 0);          \
    } } } while (0)

// 6 reads for one substep: KOFF in {0,16} bf16 within the 32-k region
#define RDS(R, KOFF, AF, BF) do {                                             \
    _Pragma("unroll")                                                         \
    for (int bm_ = 0; bm_ < 4; ++bm_) {                                       \
        const int row_ = wr * 128 + bm_ * 32 + (lane & 31);                   \
        const int kg_ = ((KOFF) >> 3) + (lane >> 5);                          \
        const int rp_ = row_ >> 1;                                            \
        const int raw_ = (row_ & 1) * 4 + kg_;                                \
        AF[bm_] = *(const s16x8*)&lA[R][rp_ * 64 + ((raw_ ^ (rp_ & 7)) << 3)]; \
    }                                                                         \
    _Pragma("unroll")                                                         \
    for (int bn_ = 0; bn_ < 2; ++bn_) {                                       \
        const int row_ = wc * 64 + bn_ * 32 + (lane & 31);                    \
        const int kg_ = ((KOFF) >> 3) + (lane >> 5);                          \
        const int rp_ = row_ >> 1;                                            \
        const int raw_ = (row_ & 1) * 4 + kg_;                                \
        BF[bn_] = *(const s16x8*)&lB[R][rp_ * 64 + ((raw_ ^ (rp_ & 7)) << 3)]; \
    }                                                                         \
} while (0)

#define MM32(AF, BF) do {                                                     \
    __builtin_amdgcn_s_setprio(1);                                            \
    _Pragma("unroll")                                                         \
    for (int bm_ = 0; bm_ < 4; ++bm_)                                         \
        _Pragma("unroll")                                                     \
        for (int bn_ = 0; bn_ < 2; ++bn_)                                     \
            acc[bm_][bn_] = __builtin_amdgcn_mfma_f32_32x32x16_bf16(          \
                AF[bm_], BF[bn_], acc[bm_][bn_], 0, 0, 0);                    \
    __builtin_amdgcn_s_setprio(0);                                            \
} while (0)

// body(p): everything between barriers except the vm-wait + barrier
#define BODYX(R, ST, SKH, SR, FIRST) do {                                     \
    RDS(R, 0, af0, bf0);                                                      \
    STAGEH(lA, Ab, SKH, ST, SR);                                              \
    STAGEH(lB, Wb, SKH, ST, SR);                                              \
    if (!(FIRST)) { L6(); MM32(af1, bf1); }                                   \
    RDS(R, 16, af1, bf1);                                                     \
    L6();                                                                     \
    MM32(af0, bf0);                                                           \
} while (0)

__global__ __launch_bounds__(512, 2)
void gemm32(const unsigned short* __restrict__ A, const unsigned short* __restrict__ W,
            unsigned short* __restrict__ C, int K) {
    const int cpx = gridDim.x >> 3;
    const int braw = blockIdx.x;
    const int bid = (braw & 7) * cpx + (braw >> 3);   // bijective: grid % 8 == 0
    const int mt = bid & 7;       // m-inner: W-panel L2 reuse
    const int nt = bid >> 3;
    const int tid = threadIdx.x;
    const int lane = tid & 63;
    const int wave = tid >> 6;
    const int wr = wave >> 2;     // 0..1
    const int wc = wave & 3;      // 0..3

    __shared__ unsigned short lA[4][8192];   // 4 regions: 256 rows x 32 k each
    __shared__ unsigned short lB[4][8192];

    f32x16 acc[4][2];
    #pragma unroll
    for (int m = 0; m < 4; ++m)
        #pragma unroll
        for (int n = 0; n < 2; ++n)
            acc[m][n] = (f32x16)(0.0f);

    const unsigned short* Ab = A + (size_t)(mt * 256) * K;
    const unsigned short* Wb = W + (size_t)(nt * 256) * K;
    const int nsteps = K >> 6;

    s16x8 af0[4], bf0[2], af1[4], bf1[2];

    // prologue: stage phase0 -> R0, phase1 -> R1; full drain; barrier
    STAGEH(lA, Ab, 0, 0, 0); STAGEH(lB, Wb, 0, 0, 0);
    STAGEH(lA, Ab, 1, 0, 1); STAGEH(lB, Wb, 1, 0, 1);
    VM0();
    BARRIER();

    // peeled t = 0 (body0 has FIRST=1: no M(-1,s1))
    BODYX(0, 1, 0, 2, 1); VM4(); BARRIER();
    BODYX(1, 1, 1, 3, 0); VM4(); BARRIER();
    BODYX(2, 2, 0, 0, 0); if (2 < nsteps) { VM4(); } else { VM0(); } BARRIER();
    BODYX(3, 2, 1, 1, 0); if (2 < nsteps) { VM4(); } else { VM0(); } BARRIER();

    for (int t = 2; t < nsteps; t += 2) {
        BODYX(0, t + 1, 0, 2, 0); VM4(); BARRIER();
        BODYX(1, t + 1, 1, 3, 0); VM4(); BARRIER();
        BODYX(2, t + 2, 0, 0, 0);
        if (t + 2 < nsteps) { VM4(); } else { VM0(); }
        BARRIER();
        BODYX(3, t + 2, 1, 1, 0);
        if (t + 2 < nsteps) { VM4(); } else { VM0(); }
        BARRIER();
    }

    // tail: last substep's MFMA
    L0();
    MM32(af1, bf1);

    // epilogue: 32x32 C/D layout col = lane&31, row = (reg&3)+8*(reg>>2)+4*(lane>>5)
    const int colb = nt * 256 + wc * 64 + (lane & 31);
    const int rowb = mt * 256 + wr * 128 + 4 * (lane >> 5);
    #pragma unroll
    for (int bm = 0; bm < 4; ++bm)
        #pragma unroll
        for (int bn = 0; bn < 2; ++bn) {
            #pragma unroll
            for (int r = 0; r < 16; ++r) {
                const int rr = rowb + bm * 32 + (r & 3) + 8 * (r >> 2);
                C[(size_t)rr * VOC + colb + bn * 32] = f2bf(acc[bm][bn][r]);
            }
        }
}

// ---------------------------------------------------------------------------
// Fallback GEMM (fp32 operands, reg-staged convert) — used only if ws too small.
// ---------------------------------------------------------------------------
__global__ __launch_bounds__(256, 2)
void gemm_bf16(const float* __restrict__ A, const float* __restrict__ W,
               unsigned short* __restrict__ C, int K) {
    const int bid = blockIdx.x;
    const int mt = bid & 15;
    const int nt = bid >> 4;
    const int tid = threadIdx.x;
    const int lane = tid & 63;
    const int wave = tid >> 6;
    const int wm = (wave >> 1) << 6;
    const int wn = (wave & 1) << 6;

    __shared__ unsigned short lds[2][2][128 * 64];

    f32x4 acc[4][4];
    #pragma unroll
    for (int m = 0; m < 4; ++m)
        #pragma unroll
        for (int n = 0; n < 4; ++n)
            acc[m][n] = (f32x4){0.f, 0.f, 0.f, 0.f};

    const float* Ab = A + (size_t)(mt * 128) * K;
    const float* Wb = W + (size_t)(nt * 128) * K;
    const int nsteps = K >> 6;

    f32x4 ra[4][2], rb[4][2];
    int rrow[4], rk16[4];
    #pragma unroll
    for (int it = 0; it < 4; ++it) {
        int idx = it * 256 + tid;
        rrow[it] = idx >> 3;
        rk16[it] = idx & 7;
    }

    auto load_regs = [&](int step) {
        const int kb = step << 6;
        #pragma unroll
        for (int it = 0; it < 4; ++it) {
            const float* pa = Ab + (size_t)rrow[it] * K + kb + rk16[it] * 8;
            const float* pw = Wb + (size_t)rrow[it] * K + kb + rk16[it] * 8;
            ra[it][0] = *(const f32x4*)pa;
            ra[it][1] = *(const f32x4*)(pa + 4);
            rb[it][0] = *(const f32x4*)pw;
            rb[it][1] = *(const f32x4*)(pw + 4);
        }
    };

    auto write_lds = [&](int buf) {
        #pragma unroll
        for (int it = 0; it < 4; ++it) {
            const int row = rrow[it];
            const int sw = rk16[it] ^ (row & 7);
            const int off = row * 64 + sw * 8;
            u32x4 pa, pw;
            pa[0] = pk2(ra[it][0][0], ra[it][0][1]);
            pa[1] = pk2(ra[it][0][2], ra[it][0][3]);
            pa[2] = pk2(ra[it][1][0], ra[it][1][1]);
            pa[3] = pk2(ra[it][1][2], ra[it][1][3]);
            pw[0] = pk2(rb[it][0][0], rb[it][0][1]);
            pw[1] = pk2(rb[it][0][2], rb[it][0][3]);
            pw[2] = pk2(rb[it][1][0], rb[it][1][1]);
            pw[3] = pk2(rb[it][1][2], rb[it][1][3]);
            *(u32x4*)&lds[buf][0][off] = pa;
            *(u32x4*)&lds[buf][1][off] = pw;
        }
    };

    auto compute = [&](int buf) {
        #pragma unroll
        for (int ks = 0; ks < 2; ++ks) {
            const int g = ks * 4 + (lane >> 4);
            const int rsel = lane & 15;
            s16x8 afr[4], bwr[4];
            #pragma unroll
            for (int m = 0; m < 4; ++m) {
                int row = wm + m * 16 + rsel;
                afr[m] = *(const s16x8*)&lds[buf][0][row * 64 + ((g ^ (row & 7)) * 8)];
            }
            #pragma unroll
            for (int n = 0; n < 4; ++n) {
                int row = wn + n * 16 + rsel;
                bwr[n] = *(const s16x8*)&lds[buf][1][row * 64 + ((g ^ (row & 7)) * 8)];
            }
            #pragma unroll
            for (int m = 0; m < 4; ++m)
                #pragma unroll
                for (int n = 0; n < 4; ++n)
                    acc[m][n] = __builtin_amdgcn_mfma_f32_16x16x32_bf16(
                        afr[m], bwr[n], acc[m][n], 0, 0, 0);
        }
    };

    load_regs(0);
    write_lds(0);
    __syncthreads();
    for (int s = 0; s < nsteps; ++s) {
        if (s + 1 < nsteps) load_regs(s + 1);
        compute(s & 1);
        if (s + 1 < nsteps) write_lds((s + 1) & 1);
        __syncthreads();
    }

    const int colb = nt * 128 + wn + (lane & 15);
    const int rowb = mt * 128 + wm + ((lane >> 4) << 2);
    #pragma unroll
    for (int m = 0; m < 4; ++m)
        #pragma unroll
        for (int n = 0; n < 4; ++n) {
            #pragma unroll
            for (int j = 0; j < 4; ++j) {
                int r = rowb + m * 16 + j;
                int c = colb + n * 16;
                C[(size_t)r * VOC + c] = f2bf(acc[m][n][j]);
            }
        }
}

// ---------------------------------------------------------------------------
// count kernel: n_non_ignore -> 1/n (or 0), and zero d_out (graph-replay safe)
// ---------------------------------------------------------------------------
__global__ void count_kernel(const int* __restrict__ label,
                             float* __restrict__ invn, float* __restrict__ out) {
    int tid = threadIdx.x;
    int c = 0;
    for (int i = tid; i < BT; i += 256) c += (label[i] != IGN) ? 1 : 0;
    #pragma unroll
    for (int o = 32; o > 0; o >>= 1) c += __shfl_xor(c, o);
    __shared__ int red[4];
    if ((tid & 63) == 0) red[tid >> 6] = c;
    __syncthreads();
    if (tid == 0) {
        int n = red[0] + red[1] + red[2] + red[3];
        invn[0] = (n > 0) ? (1.0f / (float)n) : 0.0f;
        out[0] = 0.0f;
    }
}

// ---------------------------------------------------------------------------
// JSD kernel: one block per token, 2 passes over both bf16 logit rows.
// Pass 1: online max+sumexp -> lse.  Pass 2: JSD terms -> atomicAdd.
// ---------------------------------------------------------------------------
__global__ __launch_bounds__(1024)
void jsd_kernel(const unsigned short* __restrict__ TL, const unsigned short* __restrict__ SL,
                const int* __restrict__ label, const float* __restrict__ invn,
                float* __restrict__ out) {
    const int b = blockIdx.x;
    const int tid = threadIdx.x;
    const unsigned short* tl = TL + (size_t)b * VOC;
    const unsigned short* sl = SL + (size_t)b * VOC;
    __shared__ float rmA[16], rsA[16], rmB[16], rsB[16];
    __shared__ float lse2[2];

    float mp = -3.0e38f, sp = 0.f, mq = -3.0e38f, sq = 0.f;
    for (int i = tid; i < VOC / 8; i += 1024) {
        s16x8 vt = *(const s16x8*)(tl + i * 8);
        s16x8 vs = *(const s16x8*)(sl + i * 8);
        #pragma unroll
        for (int j = 0; j < 8; ++j) {
            float x = bf2f((unsigned short)vt[j]);
            if (x > mp) { sp = sp * __expf(mp - x) + 1.0f; mp = x; }
            else        { sp += __expf(x - mp); }
            float y = bf2f((unsigned short)vs[j]);
            if (y > mq) { sq = sq * __expf(mq - y) + 1.0f; mq = y; }
            else        { sq += __expf(y - mq); }
        }
    }
    #pragma unroll
    for (int o = 32; o > 0; o >>= 1) {
        float om = __shfl_xor(mp, o), os = __shfl_xor(sp, o);
        float nm = fmaxf(mp, om);
        sp = sp * __expf(mp - nm) + os * __expf(om - nm);
        mp = nm;
        om = __shfl_xor(mq, o); os = __shfl_xor(sq, o);
        nm = fmaxf(mq, om);
        sq = sq * __expf(mq - nm) + os * __expf(om - nm);
        mq = nm;
    }
    if ((tid & 63) == 0) {
        rmA[tid >> 6] = mp; rsA[tid >> 6] = sp;
        rmB[tid >> 6] = mq; rsB[tid >> 6] = sq;
    }
    __syncthreads();
    if (tid == 0) {
        float m1 = rmA[0], s1 = 0.f, m2 = rmB[0], s2 = 0.f;
        for (int w = 1; w < 16; ++w) { m1 = fmaxf(m1, rmA[w]); m2 = fmaxf(m2, rmB[w]); }
        for (int w = 0; w < 16; ++w) {
            s1 += rsA[w] * __expf(rmA[w] - m1);
            s2 += rsB[w] * __expf(rmB[w] - m2);
        }
        lse2[0] = m1 + __logf(s1);
        lse2[1] = m2 + __logf(s2);
    }
    __syncthreads();
    const float lsep = lse2[0];
    const float lseq = lse2[1];

    float accj = 0.f;
    for (int i = tid; i < VOC / 8; i += 1024) {
        s16x8 vt = *(const s16x8*)(tl + i * 8);
        s16x8 vs = *(const s16x8*)(sl + i * 8);
        #pragma unroll
        for (int j = 0; j < 8; ++j) {
            float lp = bf2f((unsigned short)vt[j]) - lsep;
            float lq = bf2f((unsigned short)vs[j]) - lseq;
            float m0 = fmaxf(lp, lq);
            float e = __expf(-fabsf(lp - lq));
            float lm = m0 + __logf(0.5f * (1.0f + e));
            accj += 0.5f * (__expf(lp) * (lp - lm) + __expf(lq) * (lq - lm));
        }
    }
    #pragma unroll
    for (int o = 32; o > 0; o >>= 1) accj += __shfl_xor(accj, o);
    if ((tid & 63) == 0) rmA[tid >> 6] = accj;
    __syncthreads();
    if (tid == 0) {
        float a = 0.f;
        for (int w = 0; w < 16; ++w) a += rmA[w];
        if (label[b] != IGN) atomicAdd(out, a * invn[0]);
    }
}

extern "C" void kernel_launch(void* const* d_in, const int* in_sizes, int n_in,
                              void* d_out, int out_size, void* d_ws, size_t ws_size,
                              hipStream_t stream) {
    const float* s_in = (const float*)d_in[0];   // [BT, 2048]
    const float* t_in = (const float*)d_in[1];   // [BT, 4096]
    const float* Ws   = (const float*)d_in[2];   // [VOC, 2048]
    const float* Wt   = (const float*)d_in[3];   // [VOC, 4096]
    const int* label  = (const int*)d_in[4];     // [BT]
    float* out = (float*)d_out;

    const size_t L   = (size_t)BT * VOC;
    const size_t eWt = (size_t)VOC * 4096;
    const size_t eWs = (size_t)VOC * 2048;
    const size_t eAt = (size_t)BT * 4096;
    const size_t eAs = (size_t)BT * 2048;

    const size_t need_full = (2 * L + eWt + eWs + eAt + eAs) * sizeof(unsigned short) + 64;
    const size_t need_min  = 2 * L * sizeof(unsigned short) + 64;

    if (ws_size >= need_full) {
        unsigned short* logT = (unsigned short*)d_ws;
        unsigned short* logS = logT + L;
        unsigned short* Wtb  = logS + L;
        unsigned short* Wsb  = Wtb + eWt;
        unsigned short* Atb  = Wsb + eWs;
        unsigned short* Asb  = Atb + eAt;
        float* invn = (float*)(Asb + eAs);

        cvt_kernel<<<dim3(2048), dim3(256), 0, stream>>>(Wt, Wtb, (int)(eWt / 8));
        cvt_kernel<<<dim3(2048), dim3(256), 0, stream>>>(Ws, Wsb, (int)(eWs / 8));
        cvt_kernel<<<dim3(1024), dim3(256), 0, stream>>>(t_in, Atb, (int)(eAt / 8));
        cvt_kernel<<<dim3(1024), dim3(256), 0, stream>>>(s_in, Asb, (int)(eAs / 8));
        count_kernel<<<dim3(1), dim3(256), 0, stream>>>(label, invn, out);
        gemm32<<<dim3(8 * (VOC / 256)), dim3(512), 0, stream>>>(Atb, Wtb, logT, 4096);
        gemm32<<<dim3(8 * (VOC / 256)), dim3(512), 0, stream>>>(Asb, Wsb, logS, 2048);
        jsd_kernel<<<dim3(BT), dim3(1024), 0, stream>>>(logT, logS, label, invn, out);
    } else {
        if (ws_size < need_min) return;
        unsigned short* logT = (unsigned short*)d_ws;
        unsigned short* logS = logT + L;
        float* invn = (float*)(logS + L);

        count_kernel<<<dim3(1), dim3(256), 0, stream>>>(label, invn, out);
        gemm_bf16<<<dim3(16 * (VOC / 128)), dim3(256), 0, stream>>>(t_in, Wt, logT, 4096);
        gemm_bf16<<<dim3(16 * (VOC / 128)), dim3(256), 0, stream>>>(s_in, Ws, logS, 2048);
        jsd_kernel<<<dim3(BT), dim3(1024), 0, stream>>>(logT, logS, label, invn, out);
    }
}